// Round 1
// 901.551 us; speedup vs baseline: 1.0130x; 1.0130x over previous
//
#include <hip/hip_runtime.h>
#include <hip/hip_bf16.h>

typedef _Float16 f16x8 __attribute__((ext_vector_type(8)));
typedef _Float16 f16x4 __attribute__((ext_vector_type(4)));
typedef float f32x4 __attribute__((ext_vector_type(4)));

#define H 128
#define FEAT 7
#define ROWS 32

__device__ __forceinline__ float conv3(float x, float w, float b) {
    x = fmaxf(fmaf(w, x, b), 0.f);
    x = fmaxf(fmaf(w, x, b), 0.f);
    x = fmaxf(fmaf(w, x, b), 0.f);
    return x;
}
__device__ __forceinline__ float sigm(float x) {
    return __builtin_amdgcn_rcpf(1.f + __expf(-x));
}

// Pack fp32 row-major W[k][n] -> f16 MFMA fragment layout: P[((k>>3)*N + n)*8 + (k&7)]
// (A- and B-fragment lane layouts are symmetric on gfx950, so the same packing
//  serves as the A-operand of the transposed product W^T x rows^T.)
__global__ __launch_bounds__(256) void pack_weights(
    const float* __restrict__ Wr, const float* __restrict__ Wh, const float* __restrict__ Wz,
    _Float16* __restrict__ Pr, _Float16* __restrict__ Ph, _Float16* __restrict__ Pz)
{
    int idx = blockIdx.x * 256 + threadIdx.x;
    if (idx < 384 * 384) {
        int k = idx / 384, n = idx % 384;
        Pr[((size_t)(k >> 3) * 384 + n) * 8 + (k & 7)] = (_Float16)Wr[idx];
    }
    if (idx < 384 * 128) {
        int k = idx / 128, n = idx % 128;
        Ph[((size_t)(k >> 3) * 128 + n) * 8 + (k & 7)] = (_Float16)Wh[idx];
    }
    if (idx < 512 * 512) {
        int k = idx / 512, n = idx % 512;
        Pz[((size_t)(k >> 3) * 512 + n) * 8 + (k & 7)] = (_Float16)Wz[idx];
    }
}

// Fused level kernel, MFMA f16 with SWAPPED operands (weights as A, rows as B):
// accumulators hold 4 consecutive output features of one tree-row per lane,
// so all epilogues use packed b64 LDS ops and vector global stores.
template<bool LEAF>
__global__ __launch_bounds__(256, 3) void level_kernel(
    const float* __restrict__ contents,     // pre-offset, (n,7)
    const int* __restrict__ children,       // pre-offset, (n,2)
    const float* __restrict__ leafContents, // level-9 contents (LEAF only)
    const _Float16* __restrict__ embPrev,   // (!LEAF)
    _Float16* __restrict__ embOut,
    float* __restrict__ finalOut,           // non-null only at level 0
    const float* __restrict__ Wu, const float* __restrict__ bu,
    const _Float16* __restrict__ Pr, const float* __restrict__ br,
    const _Float16* __restrict__ Ph, const float* __restrict__ bh,
    const _Float16* __restrict__ Pz, const float* __restrict__ bz,
    const float* __restrict__ convw, const float* __restrict__ convb)
{
    __shared__ __align__(16) _Float16 s_hhu[ROWS][392];  // [h_L | h_R | u]
    __shared__ __align__(16) _Float16 s_x[ROWS][392];    // r*hhu; later aliased by s_hH
    _Float16 (* const s_hH)[136] = (_Float16 (*)[136])&s_x[0][0];

    const int t = threadIdx.x;
    const int row0 = blockIdx.x * ROWS;
    const int col0 = t & 127;
    const int thalf = t >> 7;
    const float cw = convw[0], cbv = convb[0];

    // Wu column for this thread (used by Stage A and the LEAF path)
    float wcol[FEAT];
#pragma unroll
    for (int k = 0; k < FEAT; k++) wcol[k] = Wu[k * H + col0];
    const float bucol = bu[col0];

    // ---- Stage A: u = conv3(c @ Wu + bu) -> s_hhu[:, 256:384]
#pragma unroll 4
    for (int i = 0; i < 16; i++) {
        int r = 2 * i + thalf;
        const float* c = contents + (size_t)(row0 + r) * FEAT;
        float acc = bucol;
#pragma unroll
        for (int k = 0; k < FEAT; k++) acc = fmaf(c[k], wcol[k], acc);
        s_hhu[r][256 + col0] = (_Float16)conv3(acc, cw, cbv);
    }

    // ---- Stage B: children embeddings
    if (LEAF) {
#pragma unroll 4
        for (int i = 0; i < 32; i++) {
            int child = children[row0 * 2 + 2 * i + thalf];
            const float* c = leafContents + (size_t)child * FEAT;
            float acc = bucol;
#pragma unroll
            for (int k = 0; k < FEAT; k++) acc = fmaf(c[k], wcol[k], acc);
            s_hhu[i][thalf * 128 + col0] = (_Float16)conv3(acc, cw, cbv);
        }
    } else {
        int rp = t >> 4, chunk = t & 15;
#pragma unroll
        for (int p = 0; p < 4; p++) {
            int cr = p * 16 + rp;
            int r = cr >> 1, s = cr & 1;
            int child = children[row0 * 2 + cr];
            uint4 v = *(const uint4*)(embPrev + (size_t)child * H + chunk * 8);
            *(uint4*)&s_hhu[r][s * 128 + chunk * 8] = v;
        }
    }
    __syncthreads();

    const int lane = t & 63;
    const int w = t >> 6;
    const int q = lane >> 4;
    const int ln = lane & 15;

    // ---- Stage C: r = sigmoid(hhu @ Wr + br); x = r * hhu  (transposed: 384 feats x 32 rows)
    {
        const f16x8* PB = (const f16x8*)Pr + (w * 96 + ln);
        f32x4 acc[6][2];
#pragma unroll
        for (int c = 0; c < 6; c++) { acc[c][0] = (f32x4){0,0,0,0}; acc[c][1] = (f32x4){0,0,0,0}; }
        f16x8 b0 = *(const f16x8*)&s_hhu[ln][q * 8];
        f16x8 b1 = *(const f16x8*)&s_hhu[16 + ln][q * 8];
        f16x8 an[6];
#pragma unroll
        for (int c = 0; c < 6; c++) an[c] = PB[(size_t)q * 384 + c * 16];
#pragma unroll
        for (int kk = 0; kk < 12; kk++) {
            f16x8 cb0 = b0, cb1 = b1;
            f16x8 ac[6];
#pragma unroll
            for (int c = 0; c < 6; c++) ac[c] = an[c];
            if (kk < 11) {
                int kb = (kk + 1) * 4 + q;
#pragma unroll
                for (int c = 0; c < 6; c++) an[c] = PB[(size_t)kb * 384 + c * 16];
                b0 = *(const f16x8*)&s_hhu[ln][(kk + 1) * 32 + q * 8];
                b1 = *(const f16x8*)&s_hhu[16 + ln][(kk + 1) * 32 + q * 8];
            }
#pragma unroll
            for (int c = 0; c < 6; c++) {
                acc[c][0] = __builtin_amdgcn_mfma_f32_16x16x32_f16(ac[c], cb0, acc[c][0], 0, 0, 0);
                acc[c][1] = __builtin_amdgcn_mfma_f32_16x16x32_f16(ac[c], cb1, acc[c][1], 0, 0, 0);
            }
        }
        // epilogue: lane holds features fb..fb+3 of row rt*16+ln
#pragma unroll
        for (int c = 0; c < 6; c++) {
            int fb = w * 96 + c * 16 + q * 4;
            f32x4 bv = *(const f32x4*)&br[fb];
#pragma unroll
            for (int rt = 0; rt < 2; rt++) {
                int row = rt * 16 + ln;
                f16x4 hh = *(const f16x4*)&s_hhu[row][fb];
                f16x4 xv;
#pragma unroll
                for (int reg = 0; reg < 4; reg++) {
                    float rv = sigm(acc[c][rt][reg] + bv[reg]);
                    xv[reg] = (_Float16)(rv * (float)hh[reg]);
                }
                *(f16x4*)&s_x[row][fb] = xv;
            }
        }
    }
    __syncthreads();

    // ---- Stage D: h_H = conv3(x @ Wh + bh)  (transposed: 128 feats x 32 rows)
    {
        const f16x8* PB = (const f16x8*)Ph + (w * 32 + ln);
        f32x4 acc[2][2];
#pragma unroll
        for (int c = 0; c < 2; c++) { acc[c][0] = (f32x4){0,0,0,0}; acc[c][1] = (f32x4){0,0,0,0}; }
        f16x8 b0 = *(const f16x8*)&s_x[ln][q * 8];
        f16x8 b1 = *(const f16x8*)&s_x[16 + ln][q * 8];
        f16x8 an[2];
#pragma unroll
        for (int c = 0; c < 2; c++) an[c] = PB[(size_t)q * 128 + c * 16];
#pragma unroll
        for (int kk = 0; kk < 12; kk++) {
            f16x8 cb0 = b0, cb1 = b1;
            f16x8 ac[2];
#pragma unroll
            for (int c = 0; c < 2; c++) ac[c] = an[c];
            if (kk < 11) {
                int kb = (kk + 1) * 4 + q;
#pragma unroll
                for (int c = 0; c < 2; c++) an[c] = PB[(size_t)kb * 128 + c * 16];
                b0 = *(const f16x8*)&s_x[ln][(kk + 1) * 32 + q * 8];
                b1 = *(const f16x8*)&s_x[16 + ln][(kk + 1) * 32 + q * 8];
            }
#pragma unroll
            for (int c = 0; c < 2; c++) {
                acc[c][0] = __builtin_amdgcn_mfma_f32_16x16x32_f16(ac[c], cb0, acc[c][0], 0, 0, 0);
                acc[c][1] = __builtin_amdgcn_mfma_f32_16x16x32_f16(ac[c], cb1, acc[c][1], 0, 0, 0);
            }
        }
        float hv[2][2][4];
#pragma unroll
        for (int c = 0; c < 2; c++) {
            int fb = w * 32 + c * 16 + q * 4;
            f32x4 bhv = *(const f32x4*)&bh[fb];
#pragma unroll
            for (int rt = 0; rt < 2; rt++)
#pragma unroll
                for (int reg = 0; reg < 4; reg++)
                    hv[c][rt][reg] = conv3(acc[c][rt][reg] + bhv[reg], cw, cbv);
        }
        __syncthreads();   // all s_x reads done before overwriting with s_hH
#pragma unroll
        for (int c = 0; c < 2; c++) {
            int fb = w * 32 + c * 16 + q * 4;
#pragma unroll
            for (int rt = 0; rt < 2; rt++) {
                f16x4 hp;
#pragma unroll
                for (int reg = 0; reg < 4; reg++) hp[reg] = (_Float16)hv[c][rt][reg];
                *(f16x4*)&s_hH[rt * 16 + ln][fb] = hp;
            }
        }
    }
    __syncthreads();

    // ---- Stage E: z = [h_H | hhu] @ Wz + bz; softmax gate; write out (transposed)
    {
        const f16x8* PBz = (const f16x8*)Pz + ln;
#pragma unroll
        for (int sub = 0; sub < 2; sub++) {
            int nb = w * 32 + sub * 16;        // z-column tile base (group 0)
            const f16x8* PL = PBz + nb;
            f32x4 acc[4][2];
#pragma unroll
            for (int g = 0; g < 4; g++) { acc[g][0] = (f32x4){0,0,0,0}; acc[g][1] = (f32x4){0,0,0,0}; }
            f16x8 b0 = *(const f16x8*)&s_hH[ln][q * 8];
            f16x8 b1 = *(const f16x8*)&s_hH[16 + ln][q * 8];
            f16x8 wn[4];
#pragma unroll
            for (int g = 0; g < 4; g++) wn[g] = PL[(size_t)q * 512 + g * 128];
#pragma unroll
            for (int kk = 0; kk < 16; kk++) {
                f16x8 cb0 = b0, cb1 = b1;
                f16x8 wc[4];
#pragma unroll
                for (int g = 0; g < 4; g++) wc[g] = wn[g];
                if (kk < 15) {
                    int kb = (kk + 1) * 4 + q;
#pragma unroll
                    for (int g = 0; g < 4; g++) wn[g] = PL[(size_t)kb * 512 + g * 128];
                    if (kk + 1 < 4) {
                        b0 = *(const f16x8*)&s_hH[ln][(kk + 1) * 32 + q * 8];
                        b1 = *(const f16x8*)&s_hH[16 + ln][(kk + 1) * 32 + q * 8];
                    } else {
                        int k0 = (kk + 1) * 32 - 128;
                        b0 = *(const f16x8*)&s_hhu[ln][k0 + q * 8];
                        b1 = *(const f16x8*)&s_hhu[16 + ln][k0 + q * 8];
                    }
                }
#pragma unroll
                for (int g = 0; g < 4; g++) {
                    acc[g][0] = __builtin_amdgcn_mfma_f32_16x16x32_f16(wc[g], cb0, acc[g][0], 0, 0, 0);
                    acc[g][1] = __builtin_amdgcn_mfma_f32_16x16x32_f16(wc[g], cb1, acc[g][1], 0, 0, 0);
                }
            }
            // epilogue: lane holds z-cols colb..colb+3 (x 4 gate groups) of row rt*16+ln
            int colb = nb + q * 4;
            f32x4 bz0 = *(const f32x4*)&bz[colb];
            f32x4 bz1 = *(const f32x4*)&bz[128 + colb];
            f32x4 bz2 = *(const f32x4*)&bz[256 + colb];
            f32x4 bz3 = *(const f32x4*)&bz[384 + colb];
#pragma unroll
            for (int rt = 0; rt < 2; rt++) {
                int row = rt * 16 + ln;
                f16x4 hH4 = *(const f16x4*)&s_hH[row][colb];
                f16x4 hL4 = *(const f16x4*)&s_hhu[row][colb];
                f16x4 hR4 = *(const f16x4*)&s_hhu[row][128 + colb];
                f16x4 u4  = *(const f16x4*)&s_hhu[row][256 + colb];
                size_t gidx = (size_t)(row0 + row) * H + colb;
                if (finalOut) {
                    f32x4 ov;
#pragma unroll
                    for (int reg = 0; reg < 4; reg++) {
                        float z0 = acc[0][rt][reg] + bz0[reg];
                        float z1 = acc[1][rt][reg] + bz1[reg];
                        float z2 = acc[2][rt][reg] + bz2[reg];
                        float z3 = acc[3][rt][reg] + bz3[reg];
                        float m = fmaxf(fmaxf(z0, z1), fmaxf(z2, z3));
                        float e0 = __expf(z0 - m), e1 = __expf(z1 - m), e2 = __expf(z2 - m), e3 = __expf(z3 - m);
                        float inv = __builtin_amdgcn_rcpf(e0 + e1 + e2 + e3);
                        ov[reg] = (e0 * (float)hH4[reg] + e1 * (float)hL4[reg] +
                                   e2 * (float)hR4[reg] + e3 * (float)u4[reg]) * inv;
                    }
                    *(f32x4*)&finalOut[gidx] = ov;
                } else {
                    f16x4 ev;
#pragma unroll
                    for (int reg = 0; reg < 4; reg++) {
                        float z0 = acc[0][rt][reg] + bz0[reg];
                        float z1 = acc[1][rt][reg] + bz1[reg];
                        float z2 = acc[2][rt][reg] + bz2[reg];
                        float z3 = acc[3][rt][reg] + bz3[reg];
                        float m = fmaxf(fmaxf(z0, z1), fmaxf(z2, z3));
                        float e0 = __expf(z0 - m), e1 = __expf(z1 - m), e2 = __expf(z2 - m), e3 = __expf(z3 - m);
                        float inv = __builtin_amdgcn_rcpf(e0 + e1 + e2 + e3);
                        ev[reg] = (_Float16)((e0 * (float)hH4[reg] + e1 * (float)hL4[reg] +
                                              e2 * (float)hR4[reg] + e3 * (float)u4[reg]) * inv);
                    }
                    *(f16x4*)&embOut[gidx] = ev;
                }
            }
        }
    }
}

extern "C" void kernel_launch(void* const* d_in, const int* in_sizes, int n_in,
                              void* d_out, int out_size, void* d_ws, size_t ws_size,
                              hipStream_t stream) {
    const float* contents = (const float*)d_in[0];
    const int*   children = (const int*)d_in[1];
    const float* Wu = (const float*)d_in[2];
    const float* bu = (const float*)d_in[3];
    const float* Wh = (const float*)d_in[4];
    const float* bh = (const float*)d_in[5];
    const float* Wz = (const float*)d_in[6];
    const float* bz = (const float*)d_in[7];
    const float* Wr = (const float*)d_in[8];
    const float* br = (const float*)d_in[9];
    const float* convw = (const float*)d_in[10];
    const float* convb = (const float*)d_in[11];
    float* out = (float*)d_out;

    // Workspace: [packed weights 1MB][bufA 64MB][bufB 64MB]
    _Float16* Pr = (_Float16*)d_ws;
    _Float16* Ph = Pr + 384 * 384;
    _Float16* Pz = Ph + 384 * 128;
    _Float16* bufA = (_Float16*)((char*)d_ws + (1 << 20));
    _Float16* bufB = bufA + (size_t)262144 * H;

    auto OFFS = [](int j) -> long long { return 1024LL * ((1LL << j) - 1); };

    pack_weights<<<(512 * 512 + 255) / 256, 256, 0, stream>>>(Wr, Wh, Wz, Pr, Ph, Pz);

    // Level 8 with fused leaf (level 9) computation
    {
        int n = 1024 << 8;
        level_kernel<true><<<n / ROWS, 256, 0, stream>>>(
            contents + OFFS(8) * FEAT, children + OFFS(8) * 2,
            contents + OFFS(9) * FEAT, nullptr, bufA, nullptr,
            Wu, bu, Pr, br, Ph, bh, Pz, bz, convw, convb);
    }

    _Float16* prev = bufA;
    _Float16* cur  = bufB;
    for (int j = 7; j >= 0; j--) {
        int n = 1024 << j;
        level_kernel<false><<<n / ROWS, 256, 0, stream>>>(
            contents + OFFS(j) * FEAT, children + OFFS(j) * 2,
            nullptr, prev, cur, (j == 0 ? out : nullptr),
            Wu, bu, Pr, br, Ph, bh, Pz, bz, convw, convb);
        _Float16* tmp = prev; prev = cur; cur = tmp;
    }
}

// Round 2
// 834.172 us; speedup vs baseline: 1.0949x; 1.0808x over previous
//
#include <hip/hip_runtime.h>
#include <hip/hip_bf16.h>

typedef _Float16 f16x8 __attribute__((ext_vector_type(8)));
typedef _Float16 f16x4 __attribute__((ext_vector_type(4)));
typedef float f32x4 __attribute__((ext_vector_type(4)));

#define H 128
#define FEAT 7
#define RB 64      // rows per block
#define NT 512     // threads per block (8 waves)

__device__ __forceinline__ float conv3(float x, float w, float b) {
    x = fmaxf(fmaf(w, x, b), 0.f);
    x = fmaxf(fmaf(w, x, b), 0.f);
    x = fmaxf(fmaf(w, x, b), 0.f);
    return x;
}
__device__ __forceinline__ float sigm(float x) {
    return __builtin_amdgcn_rcpf(1.f + __expf(-x));
}

// Pack fp32 row-major W[k][n] -> f16 MFMA fragment layout: P[((k>>3)*N + n)*8 + (k&7)]
__global__ __launch_bounds__(256) void pack_weights(
    const float* __restrict__ Wr, const float* __restrict__ Wh, const float* __restrict__ Wz,
    _Float16* __restrict__ Pr, _Float16* __restrict__ Ph, _Float16* __restrict__ Pz)
{
    int idx = blockIdx.x * 256 + threadIdx.x;
    if (idx < 384 * 384) {
        int k = idx / 384, n = idx % 384;
        Pr[((size_t)(k >> 3) * 384 + n) * 8 + (k & 7)] = (_Float16)Wr[idx];
    }
    if (idx < 384 * 128) {
        int k = idx / 128, n = idx % 128;
        Ph[((size_t)(k >> 3) * 128 + n) * 8 + (k & 7)] = (_Float16)Wh[idx];
    }
    if (idx < 512 * 512) {
        int k = idx / 512, n = idx % 512;
        Pz[((size_t)(k >> 3) * 512 + n) * 8 + (k & 7)] = (_Float16)Wz[idx];
    }
}

// Fused level kernel: 64 rows / 512 threads (8 waves). Weights as MFMA A-operand
// (rows as B) so each lane's accumulator holds 4 consecutive output features of
// one tree-row. 2x the rows of the previous version per weight stream -> halves
// L2 weight traffic (the structural bottleneck: ~916 KB of packed weights per block).
template<bool LEAF>
__global__ __launch_bounds__(NT, 2) void level_kernel(
    const float* __restrict__ contents,     // pre-offset, (n,7)
    const int* __restrict__ children,       // pre-offset, (n,2)
    const float* __restrict__ leafContents, // level-9 contents (LEAF only)
    const _Float16* __restrict__ embPrev,   // (!LEAF)
    _Float16* __restrict__ embOut,
    float* __restrict__ finalOut,           // non-null only at level 0
    const float* __restrict__ Wu, const float* __restrict__ bu,
    const _Float16* __restrict__ Pr, const float* __restrict__ br,
    const _Float16* __restrict__ Ph, const float* __restrict__ bh,
    const _Float16* __restrict__ Pz, const float* __restrict__ bz,
    const float* __restrict__ convw, const float* __restrict__ convb)
{
    __shared__ __align__(16) _Float16 s_hhu[RB][392];  // [h_L | h_R | u]
    __shared__ __align__(16) _Float16 s_x[RB][392];    // r*hhu; later aliased by s_hH
    _Float16 (* const s_hH)[136] = (_Float16 (*)[136])&s_x[0][0];

    const int t = threadIdx.x;
    const int row0 = blockIdx.x * RB;
    const int col0 = t & 127;
    const int tq = t >> 7;                  // 0..3
    const float cw = convw[0], cbv = convb[0];

    // Wu column for this thread (used by Stage A and the LEAF path)
    float wcol[FEAT];
#pragma unroll
    for (int k = 0; k < FEAT; k++) wcol[k] = Wu[k * H + col0];
    const float bucol = bu[col0];

    // ---- Stage A: u = conv3(c @ Wu + bu) -> s_hhu[:, 256:384]
#pragma unroll 4
    for (int i = 0; i < 16; i++) {
        int r = i * 4 + tq;
        const float* c = contents + (size_t)(row0 + r) * FEAT;
        float acc = bucol;
#pragma unroll
        for (int k = 0; k < FEAT; k++) acc = fmaf(c[k], wcol[k], acc);
        s_hhu[r][256 + col0] = (_Float16)conv3(acc, cw, cbv);
    }

    // ---- Stage B: children embeddings -> s_hhu[:, 0:256]
    if (LEAF) {
#pragma unroll 4
        for (int i = 0; i < 32; i++) {
            int cr = i * 4 + tq;           // 0..127
            int child = children[row0 * 2 + cr];
            const float* c = leafContents + (size_t)child * FEAT;
            float acc = bucol;
#pragma unroll
            for (int k = 0; k < FEAT; k++) acc = fmaf(c[k], wcol[k], acc);
            s_hhu[cr >> 1][(cr & 1) * 128 + col0] = (_Float16)conv3(acc, cw, cbv);
        }
    } else {
        int rp = t >> 4, chunk = t & 15;   // rp 0..31
#pragma unroll
        for (int p = 0; p < 4; p++) {
            int cr = p * 32 + rp;          // 0..127
            int child = children[row0 * 2 + cr];
            uint4 v = *(const uint4*)(embPrev + (size_t)child * H + chunk * 8);
            *(uint4*)&s_hhu[cr >> 1][(cr & 1) * 128 + chunk * 8] = v;
        }
    }
    __syncthreads();

    const int lane = t & 63;
    const int w = t >> 6;                  // 0..7
    const int q = lane >> 4;               // 0..3
    const int ln = lane & 15;

    // ---- Stage C: r = sigmoid(hhu @ Wr + br); x = r * hhu
    // wave w owns 48 output features (3 n-tiles), all 64 rows (4 m-tiles)
    {
        const f16x8* PB = (const f16x8*)Pr + (w * 48 + ln);
        f32x4 acc[3][4];
#pragma unroll
        for (int c = 0; c < 3; c++)
#pragma unroll
            for (int rt = 0; rt < 4; rt++) acc[c][rt] = (f32x4){0,0,0,0};
        f16x8 b[4];
#pragma unroll
        for (int rt = 0; rt < 4; rt++) b[rt] = *(const f16x8*)&s_hhu[rt * 16 + ln][q * 8];
        f16x8 an[3];
#pragma unroll
        for (int c = 0; c < 3; c++) an[c] = PB[(size_t)q * 384 + c * 16];
#pragma unroll
        for (int kk = 0; kk < 12; kk++) {
            f16x8 cb[4], ac[3];
#pragma unroll
            for (int rt = 0; rt < 4; rt++) cb[rt] = b[rt];
#pragma unroll
            for (int c = 0; c < 3; c++) ac[c] = an[c];
            if (kk < 11) {
                int kb = (kk + 1) * 4 + q;
#pragma unroll
                for (int c = 0; c < 3; c++) an[c] = PB[(size_t)kb * 384 + c * 16];
#pragma unroll
                for (int rt = 0; rt < 4; rt++)
                    b[rt] = *(const f16x8*)&s_hhu[rt * 16 + ln][(kk + 1) * 32 + q * 8];
            }
#pragma unroll
            for (int c = 0; c < 3; c++)
#pragma unroll
                for (int rt = 0; rt < 4; rt++)
                    acc[c][rt] = __builtin_amdgcn_mfma_f32_16x16x32_f16(ac[c], cb[rt], acc[c][rt], 0, 0, 0);
        }
        // epilogue: lane holds features fb..fb+3 of row rt*16+ln
#pragma unroll
        for (int c = 0; c < 3; c++) {
            int fb = w * 48 + c * 16 + q * 4;
            f32x4 bv = *(const f32x4*)&br[fb];
#pragma unroll
            for (int rt = 0; rt < 4; rt++) {
                int row = rt * 16 + ln;
                f16x4 hh = *(const f16x4*)&s_hhu[row][fb];
                f16x4 xv;
#pragma unroll
                for (int reg = 0; reg < 4; reg++) {
                    float rv = sigm(acc[c][rt][reg] + bv[reg]);
                    xv[reg] = (_Float16)(rv * (float)hh[reg]);
                }
                *(f16x4*)&s_x[row][fb] = xv;
            }
        }
    }
    __syncthreads();

    // ---- Stage D: h_H = conv3(x @ Wh + bh); wave w owns 16 features, 64 rows
    {
        const f16x8* PB = (const f16x8*)Ph + (w * 16 + ln);
        f32x4 acc[4];
#pragma unroll
        for (int rt = 0; rt < 4; rt++) acc[rt] = (f32x4){0,0,0,0};
        f16x8 b[4];
#pragma unroll
        for (int rt = 0; rt < 4; rt++) b[rt] = *(const f16x8*)&s_x[rt * 16 + ln][q * 8];
        f16x8 an = PB[(size_t)q * 128];
#pragma unroll
        for (int kk = 0; kk < 12; kk++) {
            f16x8 cb[4];
#pragma unroll
            for (int rt = 0; rt < 4; rt++) cb[rt] = b[rt];
            f16x8 ac = an;
            if (kk < 11) {
                int kb = (kk + 1) * 4 + q;
                an = PB[(size_t)kb * 128];
#pragma unroll
                for (int rt = 0; rt < 4; rt++)
                    b[rt] = *(const f16x8*)&s_x[rt * 16 + ln][(kk + 1) * 32 + q * 8];
            }
#pragma unroll
            for (int rt = 0; rt < 4; rt++)
                acc[rt] = __builtin_amdgcn_mfma_f32_16x16x32_f16(ac, cb[rt], acc[rt], 0, 0, 0);
        }
        float hv[4][4];
        int fb = w * 16 + q * 4;
        f32x4 bhv = *(const f32x4*)&bh[fb];
#pragma unroll
        for (int rt = 0; rt < 4; rt++)
#pragma unroll
            for (int reg = 0; reg < 4; reg++)
                hv[rt][reg] = conv3(acc[rt][reg] + bhv[reg], cw, cbv);
        __syncthreads();   // all s_x reads done before overwriting with s_hH
#pragma unroll
        for (int rt = 0; rt < 4; rt++) {
            f16x4 hp;
#pragma unroll
            for (int reg = 0; reg < 4; reg++) hp[reg] = (_Float16)hv[rt][reg];
            *(f16x4*)&s_hH[rt * 16 + ln][fb] = hp;
        }
    }
    __syncthreads();

    // ---- Stage E: z = [h_H | hhu] @ Wz + bz; softmax gate; write out
    // wave w owns 16 z-cols (x 4 gate groups at stride 128), all 64 rows
    {
        const int nb = w * 16;
        const f16x8* PL = (const f16x8*)Pz + nb + ln;
        f32x4 acc[4][4];                   // [gate group][m-tile]
#pragma unroll
        for (int g = 0; g < 4; g++)
#pragma unroll
            for (int rt = 0; rt < 4; rt++) acc[g][rt] = (f32x4){0,0,0,0};
        f16x8 b[4];
#pragma unroll
        for (int rt = 0; rt < 4; rt++) b[rt] = *(const f16x8*)&s_hH[rt * 16 + ln][q * 8];
        f16x8 wn[4];
#pragma unroll
        for (int g = 0; g < 4; g++) wn[g] = PL[(size_t)q * 512 + g * 128];
#pragma unroll
        for (int kk = 0; kk < 16; kk++) {
            f16x8 cb[4], wc[4];
#pragma unroll
            for (int rt = 0; rt < 4; rt++) cb[rt] = b[rt];
#pragma unroll
            for (int g = 0; g < 4; g++) wc[g] = wn[g];
            if (kk < 15) {
                int kb = (kk + 1) * 4 + q;
#pragma unroll
                for (int g = 0; g < 4; g++) wn[g] = PL[(size_t)kb * 512 + g * 128];
                if (kk + 1 < 4) {
#pragma unroll
                    for (int rt = 0; rt < 4; rt++)
                        b[rt] = *(const f16x8*)&s_hH[rt * 16 + ln][(kk + 1) * 32 + q * 8];
                } else {
                    int k0 = (kk + 1) * 32 - 128;
#pragma unroll
                    for (int rt = 0; rt < 4; rt++)
                        b[rt] = *(const f16x8*)&s_hhu[rt * 16 + ln][k0 + q * 8];
                }
            }
#pragma unroll
            for (int g = 0; g < 4; g++)
#pragma unroll
                for (int rt = 0; rt < 4; rt++)
                    acc[g][rt] = __builtin_amdgcn_mfma_f32_16x16x32_f16(wc[g], cb[rt], acc[g][rt], 0, 0, 0);
        }
        // epilogue: lane holds z-cols colb..colb+3 (x 4 gate groups) of rows rt*16+ln
        int colb = nb + q * 4;
        f32x4 bz0 = *(const f32x4*)&bz[colb];
        f32x4 bz1 = *(const f32x4*)&bz[128 + colb];
        f32x4 bz2 = *(const f32x4*)&bz[256 + colb];
        f32x4 bz3 = *(const f32x4*)&bz[384 + colb];
#pragma unroll
        for (int rt = 0; rt < 4; rt++) {
            int row = rt * 16 + ln;
            f16x4 hH4 = *(const f16x4*)&s_hH[row][colb];
            f16x4 hL4 = *(const f16x4*)&s_hhu[row][colb];
            f16x4 hR4 = *(const f16x4*)&s_hhu[row][128 + colb];
            f16x4 u4  = *(const f16x4*)&s_hhu[row][256 + colb];
            size_t gidx = (size_t)(row0 + row) * H + colb;
            if (finalOut) {
                f32x4 ov;
#pragma unroll
                for (int reg = 0; reg < 4; reg++) {
                    float z0 = acc[0][rt][reg] + bz0[reg];
                    float z1 = acc[1][rt][reg] + bz1[reg];
                    float z2 = acc[2][rt][reg] + bz2[reg];
                    float z3 = acc[3][rt][reg] + bz3[reg];
                    float m = fmaxf(fmaxf(z0, z1), fmaxf(z2, z3));
                    float e0 = __expf(z0 - m), e1 = __expf(z1 - m), e2 = __expf(z2 - m), e3 = __expf(z3 - m);
                    float inv = __builtin_amdgcn_rcpf(e0 + e1 + e2 + e3);
                    ov[reg] = (e0 * (float)hH4[reg] + e1 * (float)hL4[reg] +
                               e2 * (float)hR4[reg] + e3 * (float)u4[reg]) * inv;
                }
                *(f32x4*)&finalOut[gidx] = ov;
            } else {
                f16x4 ev;
#pragma unroll
                for (int reg = 0; reg < 4; reg++) {
                    float z0 = acc[0][rt][reg] + bz0[reg];
                    float z1 = acc[1][rt][reg] + bz1[reg];
                    float z2 = acc[2][rt][reg] + bz2[reg];
                    float z3 = acc[3][rt][reg] + bz3[reg];
                    float m = fmaxf(fmaxf(z0, z1), fmaxf(z2, z3));
                    float e0 = __expf(z0 - m), e1 = __expf(z1 - m), e2 = __expf(z2 - m), e3 = __expf(z3 - m);
                    float inv = __builtin_amdgcn_rcpf(e0 + e1 + e2 + e3);
                    ev[reg] = (_Float16)((e0 * (float)hH4[reg] + e1 * (float)hL4[reg] +
                                          e2 * (float)hR4[reg] + e3 * (float)u4[reg]) * inv);
                }
                *(f16x4*)&embOut[gidx] = ev;
            }
        }
    }
}

extern "C" void kernel_launch(void* const* d_in, const int* in_sizes, int n_in,
                              void* d_out, int out_size, void* d_ws, size_t ws_size,
                              hipStream_t stream) {
    const float* contents = (const float*)d_in[0];
    const int*   children = (const int*)d_in[1];
    const float* Wu = (const float*)d_in[2];
    const float* bu = (const float*)d_in[3];
    const float* Wh = (const float*)d_in[4];
    const float* bh = (const float*)d_in[5];
    const float* Wz = (const float*)d_in[6];
    const float* bz = (const float*)d_in[7];
    const float* Wr = (const float*)d_in[8];
    const float* br = (const float*)d_in[9];
    const float* convw = (const float*)d_in[10];
    const float* convb = (const float*)d_in[11];
    float* out = (float*)d_out;

    // Workspace: [packed weights 1MB][bufA 64MB][bufB 64MB]
    _Float16* Pr = (_Float16*)d_ws;
    _Float16* Ph = Pr + 384 * 384;
    _Float16* Pz = Ph + 384 * 128;
    _Float16* bufA = (_Float16*)((char*)d_ws + (1 << 20));
    _Float16* bufB = bufA + (size_t)262144 * H;

    auto OFFS = [](int j) -> long long { return 1024LL * ((1LL << j) - 1); };

    pack_weights<<<(512 * 512 + 255) / 256, 256, 0, stream>>>(Wr, Wh, Wz, Pr, Ph, Pz);

    // Level 8 with fused leaf (level 9) computation
    {
        int n = 1024 << 8;
        level_kernel<true><<<n / RB, NT, 0, stream>>>(
            contents + OFFS(8) * FEAT, children + OFFS(8) * 2,
            contents + OFFS(9) * FEAT, nullptr, bufA, nullptr,
            Wu, bu, Pr, br, Ph, bh, Pz, bz, convw, convb);
    }

    _Float16* prev = bufA;
    _Float16* cur  = bufB;
    for (int j = 7; j >= 0; j--) {
        int n = 1024 << j;
        level_kernel<false><<<n / RB, NT, 0, stream>>>(
            contents + OFFS(j) * FEAT, children + OFFS(j) * 2,
            nullptr, prev, cur, (j == 0 ? out : nullptr),
            Wu, bu, Pr, br, Ph, bh, Pz, bz, convw, convb);
        _Float16* tmp = prev; prev = cur; cur = tmp;
    }
}